// Round 9
// baseline (531.044 us; speedup 1.0000x reference)
//
#include <hip/hip_runtime.h>

#define MEXP  64
#define HDIM  256
#define INDIM 3
#define ODIM  3
#define BT    64
#define NTILE 128           /* 8192 / BT */
#define SINSC 4.774648292756860f   /* 30 / (2*pi): sin(30 z) = v_sin(z*SINSC) */

typedef __attribute__((ext_vector_type(8))) _Float16 f16x8;
typedef __attribute__((ext_vector_type(4))) _Float16 f16x4;
typedef __attribute__((ext_vector_type(4))) float    f32x4;

// Swizzled LDS byte offset for h[row][colByte]. Row stride 512B (256 ch * 2B).
// XOR of ((row ^ row>>3)&7) into byte bits 4:6 — bijective per row, same on write
// & read; spreads the stride-512B ds_read_b128 B-frag pattern across banks.
// 8B/16B-aligned accesses stay aligned (XOR touches bits >= 4 only).
__device__ __forceinline__ int swz(int row, int byteInRow) {
  return (row * 512 + byteInRow) ^ (((row ^ (row >> 3)) & 7) << 4);
}

// ---------- weight preprocessing: fp32 -> fp16 A-fragment order, SINSC folded ----
// Per (layer,m): chunk c = (ct*8+ks)*64+lane holds (as A-frag for D' = W*H^T)
// w[m][ct*16+(lane&15)][ks*32+(lane>>4)*8 + j] * SINSC, j=0..7.
__global__ void prep_hidden(const float* __restrict__ w1, const float* __restrict__ w2,
                            const float* __restrict__ w3, _Float16* __restrict__ ws) {
  int chunk = blockIdx.x * 256 + threadIdx.x;   // 3*64*8192 chunks of 8 elements
  int lm    = chunk >> 13;                      // layer*64 + m
  int c     = chunk & 8191;
  int layer = lm >> 6, m = lm & 63;
  int lane  = c & 63;
  int ctks  = c >> 6;
  int ct = ctks >> 3, ks = ctks & 7;
  int col = ct * 16 + (lane & 15);
  int k   = ks * 32 + ((lane >> 4) << 3);
  const float* w = (layer == 0) ? w1 : (layer == 1) ? w2 : w3;
  const float* src = w + ((size_t)m * HDIM + col) * HDIM + k;
  f16x8 v;
#pragma unroll
  for (int j = 0; j < 8; ++j) v[j] = (_Float16)(src[j] * SINSC);
  *(f16x8*)(ws + (size_t)chunk * 8) = v;
}

// Final layer wf[m][o][k] -> A-frags with out-rows 3..15 zero-padded (no scale).
__global__ void prep_wf(const float* __restrict__ wf, _Float16* __restrict__ ws) {
  int chunk = blockIdx.x * 256 + threadIdx.x;   // 64*512 chunks
  int m    = chunk >> 9;
  int c    = chunk & 511;                       // ks*64 + lane
  int lane = c & 63;
  int ks   = c >> 6;
  int col  = lane & 15;
  int k    = ks * 32 + ((lane >> 4) << 3);
  f16x8 v;
  if (col < ODIM) {
    const float* src = wf + ((size_t)m * ODIM + col) * HDIM + k;
#pragma unroll
    for (int j = 0; j < 8; ++j) v[j] = (_Float16)src[j];
  } else {
#pragma unroll
    for (int j = 0; j < 8; ++j) v[j] = (_Float16)0.0f;
  }
  *(f16x8*)(ws + (size_t)chunk * 8) = v;
}

// ---------- fused SIREN ----------
// Hidden layer, swapped orientation: D'[ch][row] = W'[ch][k] * H[k][row].
// chW=64: each wave owns 64 output channels x all 64 rows (4 ct x 4 rt tiles).
// Halves LDS h-tile re-reads vs chW=32 (the round-8 bottleneck: LDS pipe+conflict
// ~31% of cycles). Bias is folded into the accumulator init (saves 64 fmaf/thread).
__device__ __forceinline__ void hidden_layer(char* hb, const _Float16* __restrict__ wl,
                                             const float* __restrict__ bptr,
                                             int wid, int lane, int g) {
  // bias init: lane's channels are c0(ct) = wid*64 + ct*16 + g*4, 4 consecutive.
  f32x4 acc[4][4];
#pragma unroll
  for (int ct = 0; ct < 4; ++ct) {
    f32x4 binit = *(const f32x4*)(bptr + wid * 64 + ct * 16 + g * 4);
    binit *= SINSC;                            // pre-sin arg is SINSC*(Wh+b)
#pragma unroll
    for (int rt = 0; rt < 4; ++rt) acc[rt][ct] = binit;
  }
  const f16x8* wfrag = (const f16x8*)wl;       // chunk (ctg*8+ks)*64+lane
  f16x8 A[4];
#pragma unroll
  for (int ct = 0; ct < 4; ++ct)               // prefetch ks=0, 4 streams
    A[ct] = wfrag[((wid * 4 + ct) * 8 + 0) * 64 + lane];
#pragma unroll
  for (int ks = 0; ks < 8; ++ks) {
    f16x8 a[4];
#pragma unroll
    for (int ct = 0; ct < 4; ++ct) a[ct] = A[ct];
    if (ks < 7) {
#pragma unroll
      for (int ct = 0; ct < 4; ++ct)           // prefetch next ks
        A[ct] = wfrag[((wid * 4 + ct) * 8 + ks + 1) * 64 + lane];
    }
#pragma unroll
    for (int rt = 0; rt < 4; ++rt) {
      f16x8 b = *(const f16x8*)(hb + swz(rt * 16 + (lane & 15), ks * 64 + g * 16));
#pragma unroll
      for (int ct = 0; ct < 4; ++ct)
        acc[rt][ct] = __builtin_amdgcn_mfma_f32_16x16x32_f16(a[ct], b, acc[rt][ct], 0, 0, 0);
    }
  }
  __syncthreads();   // all reads of hb complete before overwrite
#pragma unroll
  for (int ct = 0; ct < 4; ++ct) {
    int c0 = wid * 64 + ct * 16 + g * 4;       // 4 consecutive channels per lane
#pragma unroll
    for (int rt = 0; rt < 4; ++rt) {
      f16x4 v;
#pragma unroll
      for (int t = 0; t < 4; ++t)
        v[t] = (_Float16)__builtin_amdgcn_sinf(acc[rt][ct][t]);
      *(f16x4*)(hb + swz(rt * 16 + (lane & 15), c0 * 2)) = v;   // ds_write_b64
    }
  }
  __syncthreads();
}

// launch_bounds note: (512,4) was interpreted as 4 *blocks*/CU -> 32 waves/CU ->
// VGPR cap 64 -> acc spilled (round 7: 1.8 GB scratch traffic). (256,4) yields a
// 128-reg cap under either interpretation (4 blk x 4 waves, or 4 waves/EU).
__global__ __launch_bounds__(256, 4)
void siren_fused(const float* __restrict__ x, const float* __restrict__ w0,
                 const float* __restrict__ b0, const float* __restrict__ b1,
                 const float* __restrict__ b2, const float* __restrict__ b3,
                 const float* __restrict__ bfin, const _Float16* __restrict__ wh,
                 const _Float16* __restrict__ wff, float* __restrict__ out) {
  __shared__ _Float16 hbuf[BT * HDIM];   // 32 KB swizzled fp16 h tile
  char* hb = (char*)hbuf;

  int tid  = threadIdx.x;
  int lane = tid & 63;
  int wid  = tid >> 6;
  int g    = lane >> 4;
  int id   = blockIdx.x;
  // XCD swizzle: XCD = id%8 gets 8 experts -> per-XCD L2 weight set 8*3*128KB = 3MB.
  int m    = ((id & 7) << 3) + ((id >> 3) >> 7);
  int tile = (id >> 3) & (NTILE - 1);

  // ---- layer 0: [BT,3] x w0[m][H,3]^T, fp32 VALU (K=3). One column per thread. ----
  {
    int col = tid;
    const float* wp = w0 + ((size_t)m * HDIM + col) * INDIM;
    float wc0 = wp[0], wc1 = wp[1], wc2 = wp[2];
    float bc  = b0[m * HDIM + col] * SINSC;
    const float* xp = x + (size_t)tile * BT * INDIM;   // block-uniform -> s_load
#pragma unroll 4
    for (int r = 0; r < BT; ++r) {
      float z = fmaf(xp[r * 3 + 2], wc2, fmaf(xp[r * 3 + 1], wc1, xp[r * 3] * wc0));
      float h = __builtin_amdgcn_sinf(fmaf(z, SINSC, bc));
      *(_Float16*)(hb + swz(r, col * 2)) = (_Float16)h;
    }
  }
  __syncthreads();

  hidden_layer(hb, wh + ((size_t)0 * MEXP + m) * (HDIM * HDIM), b1 + m * HDIM, wid, lane, g);
  hidden_layer(hb, wh + ((size_t)1 * MEXP + m) * (HDIM * HDIM), b2 + m * HDIM, wid, lane, g);
  hidden_layer(hb, wh + ((size_t)2 * MEXP + m) * (HDIM * HDIM), b3 + m * HDIM, wid, lane, g);

  // ---- final layer: D'[o][row], one 16-row strip per wave; lanes g==0 hold o=t ----
  {
    f32x4 facc = {};
    const f16x8* wfrag = (const f16x8*)(wff + (size_t)m * (16 * HDIM));
#pragma unroll
    for (int ks = 0; ks < 8; ++ks) {
      f16x8 b = *(const f16x8*)(hb + swz(wid * 16 + (lane & 15), ks * 64 + g * 16));
      f16x8 a = wfrag[ks * 64 + lane];
      facc = __builtin_amdgcn_mfma_f32_16x16x32_f16(a, b, facc, 0, 0, 0);
    }
    if (g == 0) {
      size_t r = (size_t)tile * BT + wid * 16 + (lane & 15);
#pragma unroll
      for (int t = 0; t < 3; ++t)
        out[(r * MEXP + m) * ODIM + t] = facc[t] + bfin[m * ODIM + t];
    }
  }
}

extern "C" void kernel_launch(void* const* d_in, const int* in_sizes, int n_in,
                              void* d_out, int out_size, void* d_ws, size_t ws_size,
                              hipStream_t stream) {
  (void)in_sizes; (void)n_in; (void)out_size; (void)ws_size;
  const float* x  = (const float*)d_in[0];
  const float* w0 = (const float*)d_in[1];
  const float* b0 = (const float*)d_in[2];
  const float* w1 = (const float*)d_in[3];
  const float* b1 = (const float*)d_in[4];
  const float* w2 = (const float*)d_in[5];
  const float* b2 = (const float*)d_in[6];
  const float* w3 = (const float*)d_in[7];
  const float* b3 = (const float*)d_in[8];
  const float* wf = (const float*)d_in[9];
  const float* bf = (const float*)d_in[10];

  _Float16* wh  = (_Float16*)d_ws;                       // 3*64*65536 fp16 = 24 MB
  _Float16* wff = wh + (size_t)3 * MEXP * HDIM * HDIM;   // + 64*4096 fp16 = 0.5 MB

  prep_hidden<<<6144, 256, 0, stream>>>(w1, w2, w3, wh);
  prep_wf<<<128, 256, 0, stream>>>(wf, wff);
  siren_fused<<<8192, 256, 0, stream>>>(x, w0, b0, b1, b2, b3, bf, wh, wff, (float*)d_out);
}

// Round 10
// 375.669 us; speedup vs baseline: 1.4136x; 1.4136x over previous
//
#include <hip/hip_runtime.h>

#define MEXP  64
#define HDIM  256
#define INDIM 3
#define ODIM  3
#define BT    64
#define NTILE 128           /* 8192 / BT */
#define SINSC 4.774648292756860f   /* 30 / (2*pi): sin(30 z) = v_sin(z*SINSC) */

typedef __attribute__((ext_vector_type(8))) _Float16 f16x8;
typedef __attribute__((ext_vector_type(4))) _Float16 f16x4;
typedef __attribute__((ext_vector_type(4))) float    f32x4;

// Swizzled LDS byte offset for h[row][colByte]. Row stride 512B (256 ch * 2B).
// XOR of ((row ^ row>>3)&7) into byte bits 4:6 — bijective per row, same on write
// & read; spreads the stride-512B ds_read_b128 B-frag pattern across banks.
// 8B/16B-aligned accesses stay aligned (XOR touches bits >= 4 only).
__device__ __forceinline__ int swz(int row, int byteInRow) {
  return (row * 512 + byteInRow) ^ (((row ^ (row >> 3)) & 7) << 4);
}

// ---------- weight preprocessing: fp32 -> fp16 A-fragment order, SINSC folded ----
// Per (layer,m): chunk c = (ct*8+ks)*64+lane holds (as A-frag for D' = W*H^T)
// w[m][ct*16+(lane&15)][ks*32+(lane>>4)*8 + j] * SINSC, j=0..7.
__global__ void prep_hidden(const float* __restrict__ w1, const float* __restrict__ w2,
                            const float* __restrict__ w3, _Float16* __restrict__ ws) {
  int chunk = blockIdx.x * 256 + threadIdx.x;   // 3*64*8192 chunks of 8 elements
  int lm    = chunk >> 13;                      // layer*64 + m
  int c     = chunk & 8191;
  int layer = lm >> 6, m = lm & 63;
  int lane  = c & 63;
  int ctks  = c >> 6;
  int ct = ctks >> 3, ks = ctks & 7;
  int col = ct * 16 + (lane & 15);
  int k   = ks * 32 + ((lane >> 4) << 3);
  const float* w = (layer == 0) ? w1 : (layer == 1) ? w2 : w3;
  const float* src = w + ((size_t)m * HDIM + col) * HDIM + k;
  f16x8 v;
#pragma unroll
  for (int j = 0; j < 8; ++j) v[j] = (_Float16)(src[j] * SINSC);
  *(f16x8*)(ws + (size_t)chunk * 8) = v;
}

// Final layer wf[m][o][k] -> A-frags with out-rows 3..15 zero-padded (no scale).
__global__ void prep_wf(const float* __restrict__ wf, _Float16* __restrict__ ws) {
  int chunk = blockIdx.x * 256 + threadIdx.x;   // 64*512 chunks
  int m    = chunk >> 9;
  int c    = chunk & 511;                       // ks*64 + lane
  int lane = c & 63;
  int ks   = c >> 6;
  int col  = lane & 15;
  int k    = ks * 32 + ((lane >> 4) << 3);
  f16x8 v;
  if (col < ODIM) {
    const float* src = wf + ((size_t)m * ODIM + col) * HDIM + k;
#pragma unroll
    for (int j = 0; j < 8; ++j) v[j] = (_Float16)src[j];
  } else {
#pragma unroll
    for (int j = 0; j < 8; ++j) v[j] = (_Float16)0.0f;
  }
  *(f16x8*)(ws + (size_t)chunk * 8) = v;
}

// ---------- fused SIREN ----------
// Hidden layer, swapped orientation: D'[ch][row] = W'[ch][k] * H[k][row].
// chW=64: each wave owns 64 output channels x all 64 rows (4 ct x 4 rt tiles).
// Halves LDS h-tile re-reads vs chW=32 (the round-8 bottleneck: LDS pipe+conflict
// ~31% of cycles; conflicts dropped 3.25e7->1.99e7 as predicted). Bias is folded
// into the accumulator init (saves 64 fmaf/thread).
__device__ __forceinline__ void hidden_layer(char* hb, const _Float16* __restrict__ wl,
                                             const float* __restrict__ bptr,
                                             int wid, int lane, int g) {
  // bias init: lane's channels are c0(ct) = wid*64 + ct*16 + g*4, 4 consecutive.
  f32x4 acc[4][4];
#pragma unroll
  for (int ct = 0; ct < 4; ++ct) {
    f32x4 binit = *(const f32x4*)(bptr + wid * 64 + ct * 16 + g * 4);
    binit *= SINSC;                            // pre-sin arg is SINSC*(Wh+b)
#pragma unroll
    for (int rt = 0; rt < 4; ++rt) acc[rt][ct] = binit;
  }
  const f16x8* wfrag = (const f16x8*)wl;       // chunk (ctg*8+ks)*64+lane
  f16x8 A[4];
#pragma unroll
  for (int ct = 0; ct < 4; ++ct)               // prefetch ks=0, 4 streams
    A[ct] = wfrag[((wid * 4 + ct) * 8 + 0) * 64 + lane];
#pragma unroll
  for (int ks = 0; ks < 8; ++ks) {
    f16x8 a[4];
#pragma unroll
    for (int ct = 0; ct < 4; ++ct) a[ct] = A[ct];
    if (ks < 7) {
#pragma unroll
      for (int ct = 0; ct < 4; ++ct)           // prefetch next ks
        A[ct] = wfrag[((wid * 4 + ct) * 8 + ks + 1) * 64 + lane];
    }
#pragma unroll
    for (int rt = 0; rt < 4; ++rt) {
      f16x8 b = *(const f16x8*)(hb + swz(rt * 16 + (lane & 15), ks * 64 + g * 16));
#pragma unroll
      for (int ct = 0; ct < 4; ++ct)
        acc[rt][ct] = __builtin_amdgcn_mfma_f32_16x16x32_f16(a[ct], b, acc[rt][ct], 0, 0, 0);
    }
  }
  __syncthreads();   // all reads of hb complete before overwrite
#pragma unroll
  for (int ct = 0; ct < 4; ++ct) {
    int c0 = wid * 64 + ct * 16 + g * 4;       // 4 consecutive channels per lane
#pragma unroll
    for (int rt = 0; rt < 4; ++rt) {
      f16x4 v;
#pragma unroll
      for (int t = 0; t < 4; ++t)
        v[t] = (_Float16)__builtin_amdgcn_sinf(acc[rt][ct][t]);
      *(f16x4*)(hb + swz(rt * 16 + (lane & 15), c0 * 2)) = v;   // ds_write_b64
    }
  }
  __syncthreads();
}

// launch_bounds EMPIRICAL rule (this toolchain, gfx950, measured rounds 7-9):
// VGPR cap = 256/arg2 regardless of block size: (512,4)->64, (256,4)->64,
// (512,2)->128. Working set ~115 regs => arg2 MUST be 2. At 128 VGPR the HW
// runs 4 waves/SIMD -> 4 blocks/CU (LDS 4x32KB=128KB <= 160KB).
__global__ __launch_bounds__(256, 2)
void siren_fused(const float* __restrict__ x, const float* __restrict__ w0,
                 const float* __restrict__ b0, const float* __restrict__ b1,
                 const float* __restrict__ b2, const float* __restrict__ b3,
                 const float* __restrict__ bfin, const _Float16* __restrict__ wh,
                 const _Float16* __restrict__ wff, float* __restrict__ out) {
  __shared__ _Float16 hbuf[BT * HDIM];   // 32 KB swizzled fp16 h tile
  char* hb = (char*)hbuf;

  int tid  = threadIdx.x;
  int lane = tid & 63;
  int wid  = tid >> 6;
  int g    = lane >> 4;
  int id   = blockIdx.x;
  // XCD swizzle: XCD = id%8 gets 8 experts -> per-XCD L2 weight set 8*3*128KB = 3MB.
  int m    = ((id & 7) << 3) + ((id >> 3) >> 7);
  int tile = (id >> 3) & (NTILE - 1);

  // ---- layer 0: [BT,3] x w0[m][H,3]^T, fp32 VALU (K=3). One column per thread. ----
  {
    int col = tid;
    const float* wp = w0 + ((size_t)m * HDIM + col) * INDIM;
    float wc0 = wp[0], wc1 = wp[1], wc2 = wp[2];
    float bc  = b0[m * HDIM + col] * SINSC;
    const float* xp = x + (size_t)tile * BT * INDIM;   // block-uniform -> s_load
#pragma unroll 4
    for (int r = 0; r < BT; ++r) {
      float z = fmaf(xp[r * 3 + 2], wc2, fmaf(xp[r * 3 + 1], wc1, xp[r * 3] * wc0));
      float h = __builtin_amdgcn_sinf(fmaf(z, SINSC, bc));
      *(_Float16*)(hb + swz(r, col * 2)) = (_Float16)h;
    }
  }
  __syncthreads();

  hidden_layer(hb, wh + ((size_t)0 * MEXP + m) * (HDIM * HDIM), b1 + m * HDIM, wid, lane, g);
  hidden_layer(hb, wh + ((size_t)1 * MEXP + m) * (HDIM * HDIM), b2 + m * HDIM, wid, lane, g);
  hidden_layer(hb, wh + ((size_t)2 * MEXP + m) * (HDIM * HDIM), b3 + m * HDIM, wid, lane, g);

  // ---- final layer: D'[o][row], one 16-row strip per wave; lanes g==0 hold o=t ----
  {
    f32x4 facc = {};
    const f16x8* wfrag = (const f16x8*)(wff + (size_t)m * (16 * HDIM));
#pragma unroll
    for (int ks = 0; ks < 8; ++ks) {
      f16x8 b = *(const f16x8*)(hb + swz(wid * 16 + (lane & 15), ks * 64 + g * 16));
      f16x8 a = wfrag[ks * 64 + lane];
      facc = __builtin_amdgcn_mfma_f32_16x16x32_f16(a, b, facc, 0, 0, 0);
    }
    if (g == 0) {
      size_t r = (size_t)tile * BT + wid * 16 + (lane & 15);
#pragma unroll
      for (int t = 0; t < 3; ++t)
        out[(r * MEXP + m) * ODIM + t] = facc[t] + bfin[m * ODIM + t];
    }
  }
}

extern "C" void kernel_launch(void* const* d_in, const int* in_sizes, int n_in,
                              void* d_out, int out_size, void* d_ws, size_t ws_size,
                              hipStream_t stream) {
  (void)in_sizes; (void)n_in; (void)out_size; (void)ws_size;
  const float* x  = (const float*)d_in[0];
  const float* w0 = (const float*)d_in[1];
  const float* b0 = (const float*)d_in[2];
  const float* w1 = (const float*)d_in[3];
  const float* b1 = (const float*)d_in[4];
  const float* w2 = (const float*)d_in[5];
  const float* b2 = (const float*)d_in[6];
  const float* w3 = (const float*)d_in[7];
  const float* b3 = (const float*)d_in[8];
  const float* wf = (const float*)d_in[9];
  const float* bf = (const float*)d_in[10];

  _Float16* wh  = (_Float16*)d_ws;                       // 3*64*65536 fp16 = 24 MB
  _Float16* wff = wh + (size_t)3 * MEXP * HDIM * HDIM;   // + 64*4096 fp16 = 0.5 MB

  prep_hidden<<<6144, 256, 0, stream>>>(w1, w2, w3, wh);
  prep_wf<<<128, 256, 0, stream>>>(wf, wff);
  siren_fused<<<8192, 256, 0, stream>>>(x, w0, b0, b1, b2, b3, bf, wh, wff, (float*)d_out);
}

// Round 12
// 335.603 us; speedup vs baseline: 1.5824x; 1.1194x over previous
//
#include <hip/hip_runtime.h>

#define MEXP  64
#define HDIM  256
#define INDIM 3
#define ODIM  3
#define BT    64
#define NTILE 128           /* 8192 / BT */
#define SINSC 4.774648292756860f   /* 30 / (2*pi): sin(30 z) = v_sin(z*SINSC) */

typedef __attribute__((ext_vector_type(8))) _Float16 f16x8;
typedef __attribute__((ext_vector_type(4))) _Float16 f16x4;
typedef __attribute__((ext_vector_type(4))) float    f32x4;

// Swizzled LDS byte offset for h[row][colByte]. Row stride 512B (256 ch * 2B).
// XOR of ((row ^ row>>3)&7) into byte bits 4:6 — bijective per row, same on write
// & read. 8B/16B-aligned accesses stay aligned (XOR touches bits >= 4 only).
__device__ __forceinline__ int swz(int row, int byteInRow) {
  return (row * 512 + byteInRow) ^ (((row ^ (row >> 3)) & 7) << 4);
}

// ---------- weight preprocessing: fp32 -> fp16 A-fragment order, SINSC folded ----
// Per (layer,m): chunk c = (ct*8+ks)*64+lane holds (as A-frag for D' = W*H^T)
// w[m][ct*16+(lane&15)][ks*32+(lane>>4)*8 + j] * SINSC, j=0..7.
__global__ void prep_hidden(const float* __restrict__ w1, const float* __restrict__ w2,
                            const float* __restrict__ w3, _Float16* __restrict__ ws) {
  int chunk = blockIdx.x * 256 + threadIdx.x;   // 3*64*8192 chunks of 8 elements
  int lm    = chunk >> 13;                      // layer*64 + m
  int c     = chunk & 8191;
  int layer = lm >> 6, m = lm & 63;
  int lane  = c & 63;
  int ctks  = c >> 6;
  int ct = ctks >> 3, ks = ctks & 7;
  int col = ct * 16 + (lane & 15);
  int k   = ks * 32 + ((lane >> 4) << 3);
  const float* w = (layer == 0) ? w1 : (layer == 1) ? w2 : w3;
  const float* src = w + ((size_t)m * HDIM + col) * HDIM + k;
  f16x8 v;
#pragma unroll
  for (int j = 0; j < 8; ++j) v[j] = (_Float16)(src[j] * SINSC);
  *(f16x8*)(ws + (size_t)chunk * 8) = v;
}

// Final layer wf[m][o][k] -> A-frags with out-rows 3..15 zero-padded (no scale).
__global__ void prep_wf(const float* __restrict__ wf, _Float16* __restrict__ ws) {
  int chunk = blockIdx.x * 256 + threadIdx.x;   // 64*512 chunks
  int m    = chunk >> 9;
  int c    = chunk & 511;                       // ks*64 + lane
  int lane = c & 63;
  int ks   = c >> 6;
  int col  = lane & 15;
  int k    = ks * 32 + ((lane >> 4) << 3);
  f16x8 v;
  if (col < ODIM) {
    const float* src = wf + ((size_t)m * ODIM + col) * HDIM + k;
#pragma unroll
    for (int j = 0; j < 8; ++j) v[j] = (_Float16)src[j];
  } else {
#pragma unroll
    for (int j = 0; j < 8; ++j) v[j] = (_Float16)0.0f;
  }
  *(f16x8*)(ws + (size_t)chunk * 8) = v;
}

// Layer-0 weights w0[m][col][0..2] -> K=32 A-frags with hi/lo split so ONE
// 16x16x32 MFMA computes the K=3 dot at ~fp32 precision:
//   k 0-2  = hi(w*SINSC)   (pairs with x_hi)
//   k 8-10 = lo(w*SINSC)   (pairs with x_hi)
//   k16-18 = hi(w*SINSC)   (pairs with x_lo)     rest zero.
// chunk c = m*1024 + ct*64 + lane; col = ct*16+(lane&15); k = (lane>>4)*8+j.
__global__ void prep_w0(const float* __restrict__ w0, _Float16* __restrict__ ws) {
  int c    = blockIdx.x * 256 + threadIdx.x;    // 64*16*64 chunks
  int m    = c >> 10;
  int ct   = (c >> 6) & 15;
  int lane = c & 63;
  int col  = ct * 16 + (lane & 15);
  int g    = lane >> 4;
  const float* src = w0 + ((size_t)m * HDIM + col) * INDIM;
  f16x8 v = {};
  if (g == 0 || g == 2) {
#pragma unroll
    for (int j = 0; j < 3; ++j) v[j] = (_Float16)(src[j] * SINSC);
  } else if (g == 1) {
#pragma unroll
    for (int j = 0; j < 3; ++j) {
      float w = src[j] * SINSC;
      _Float16 hi = (_Float16)w;
      v[j] = (_Float16)(w - (float)hi);
    }
  }
  *(f16x8*)(ws + (size_t)c * 8) = v;
}

// ---------- fused SIREN ----------
__device__ __forceinline__ void epilogue_sin(char* hb, f32x4 (&acc)[4][4],
                                             int wid, int lane, int g) {
#pragma unroll
  for (int ct = 0; ct < 4; ++ct) {
    int c0 = wid * 64 + ct * 16 + g * 4;        // 4 consecutive channels per lane
#pragma unroll
    for (int rt = 0; rt < 4; ++rt) {
      f16x4 v;
#pragma unroll
      for (int t = 0; t < 4; ++t)
        v[t] = (_Float16)__builtin_amdgcn_sinf(acc[rt][ct][t]);
      *(f16x4*)(hb + swz(rt * 16 + (lane & 15), c0 * 2)) = v;   // ds_write_b64
    }
  }
}

// Hidden layer D'[ch][row] = W'[ch][k]*H[k][row]. On ENTRY A[] holds this
// layer's ks=0 A-frags (prefetched by the previous layer); on EXIT A[] holds
// the NEXT layer's ks=0 frags (A[ct] = nextp[ct*ns]), issued right after the
// last MFMA so L2 latency hides under the epilogue + 2 barriers.
__device__ __forceinline__ void hidden_layer(char* hb, f16x8 (&A)[4],
                                             const _Float16* __restrict__ wl,
                                             const f16x8* __restrict__ nextp, int ns,
                                             const float* __restrict__ bptr,
                                             int wid, int lane, int g) {
  f32x4 acc[4][4];
#pragma unroll
  for (int ct = 0; ct < 4; ++ct) {
    f32x4 binit = *(const f32x4*)(bptr + wid * 64 + ct * 16 + g * 4);
    binit *= SINSC;                             // pre-sin arg is SINSC*(Wh+b)
#pragma unroll
    for (int rt = 0; rt < 4; ++rt) acc[rt][ct] = binit;
  }
  const f16x8* wfrag = (const f16x8*)wl;        // chunk (ctg*8+ks)*64+lane
#pragma unroll
  for (int ks = 0; ks < 8; ++ks) {
    f16x8 a[4];
#pragma unroll
    for (int ct = 0; ct < 4; ++ct) a[ct] = A[ct];
    if (ks < 7) {
#pragma unroll
      for (int ct = 0; ct < 4; ++ct)            // prefetch next ks
        A[ct] = wfrag[((wid * 4 + ct) * 8 + ks + 1) * 64 + lane];
    }
#pragma unroll
    for (int rt = 0; rt < 4; ++rt) {
      f16x8 b = *(const f16x8*)(hb + swz(rt * 16 + (lane & 15), ks * 64 + g * 16));
#pragma unroll
      for (int ct = 0; ct < 4; ++ct)
        acc[rt][ct] = __builtin_amdgcn_mfma_f32_16x16x32_f16(a[ct], b, acc[rt][ct], 0, 0, 0);
    }
  }
  // prefetch NEXT layer's ks=0 frags while acc drains into the epilogue
#pragma unroll
  for (int ct = 0; ct < 4; ++ct) A[ct] = nextp[ct * ns];
  __syncthreads();   // all reads of hb complete before overwrite
  epilogue_sin(hb, acc, wid, lane, g);
  __syncthreads();
}

// launch_bounds EMPIRICAL rule (this toolchain, gfx950, rounds 7-10):
// VGPR cap = 256/arg2 regardless of block size: (512,4)->64, (256,4)->64,
// (512,2)->128, (256,2)->128(used 96). Working set ~115 regs => arg2 = 2.
__global__ __launch_bounds__(256, 2)
void siren_fused(const float* __restrict__ x, const float* __restrict__ b0,
                 const float* __restrict__ b1, const float* __restrict__ b2,
                 const float* __restrict__ b3, const float* __restrict__ bfin,
                 const _Float16* __restrict__ w0f, const _Float16* __restrict__ wh,
                 const _Float16* __restrict__ wff, float* __restrict__ out) {
  __shared__ __align__(16) _Float16 hbuf[BT * HDIM];   // 32 KB swizzled h tile
  __shared__ __align__(16) _Float16 xbuf[BT * 40];     // 5 KB x frags, 80B row stride
  char* hb = (char*)hbuf;

  int tid  = threadIdx.x;
  int lane = tid & 63;
  int wid  = tid >> 6;
  int g    = lane >> 4;
  int id   = blockIdx.x;
  // XCD swizzle: XCD = id%8 gets 8 experts -> per-XCD L2 weight set ~3MB.
  int m    = ((id & 7) << 3) + ((id >> 3) >> 7);
  int tile = (id >> 3) & (NTILE - 1);

  // issue layer-0 weight loads FIRST; latency hides under x staging
  const f16x8* w0p = (const f16x8*)(w0f + (size_t)m * (16 * 64 * 8));
  f16x8 A[4];
#pragma unroll
  for (int ct = 0; ct < 4; ++ct) A[ct] = w0p[(wid * 4 + ct) * 64 + lane];

  // stage x as K=32 B-frags with hi/lo split: which 0,1 = x_hi; 2 = x_lo; 3 = 0
  {
    int row = tid & 63, which = tid >> 6;
    const float* xp = x + ((size_t)tile * BT + row) * INDIM;
    f16x8 v = {};
    if (which < 2) {
#pragma unroll
      for (int j = 0; j < 3; ++j) v[j] = (_Float16)xp[j];
    } else if (which == 2) {
#pragma unroll
      for (int j = 0; j < 3; ++j) {
        float xv = xp[j];
        _Float16 hi = (_Float16)xv;
        v[j] = (_Float16)(xv - (float)hi);
      }
    }
    *(f16x8*)((char*)xbuf + row * 80 + which * 16) = v;
  }
  __syncthreads();

  const _Float16* wl1 = wh + ((size_t)0 * MEXP + m) * (HDIM * HDIM);
  const _Float16* wl2 = wh + ((size_t)1 * MEXP + m) * (HDIM * HDIM);
  const _Float16* wl3 = wh + ((size_t)2 * MEXP + m) * (HDIM * HDIM);
  const f16x8*    wfp = (const f16x8*)(wff + (size_t)m * (16 * HDIM));

  // ---- layer 0: one K=32 MFMA per (rt,ct); hi/lo split gives ~fp32 accuracy ----
  {
    f32x4 acc[4][4];
#pragma unroll
    for (int ct = 0; ct < 4; ++ct) {
      f32x4 binit = *(const f32x4*)(b0 + m * HDIM + wid * 64 + ct * 16 + g * 4);
      binit *= SINSC;
#pragma unroll
      for (int rt = 0; rt < 4; ++rt) acc[rt][ct] = binit;
    }
#pragma unroll
    for (int rt = 0; rt < 4; ++rt) {
      f16x8 b = *(const f16x8*)((char*)xbuf + (rt * 16 + (lane & 15)) * 80 + g * 16);
#pragma unroll
      for (int ct = 0; ct < 4; ++ct)
        acc[rt][ct] = __builtin_amdgcn_mfma_f32_16x16x32_f16(A[ct], b, acc[rt][ct], 0, 0, 0);
    }
    // prefetch layer-1 ks=0 frags
    const f16x8* np = (const f16x8*)wl1 + wid * 2048 + lane;
#pragma unroll
    for (int ct = 0; ct < 4; ++ct) A[ct] = np[ct * 512];
    epilogue_sin(hb, acc, wid, lane, g);   // nobody has read hb yet: no pre-barrier
    __syncthreads();
  }

  hidden_layer(hb, A, wl1, (const f16x8*)wl2 + wid * 2048 + lane, 512,
               b1 + m * HDIM, wid, lane, g);
  hidden_layer(hb, A, wl2, (const f16x8*)wl3 + wid * 2048 + lane, 512,
               b2 + m * HDIM, wid, lane, g);
  hidden_layer(hb, A, wl3, wfp + lane, 64,          // next = wff chunks ks=0..3
               b3 + m * HDIM, wid, lane, g);

  // ---- final layer: D'[o][row], one 16-row strip per wave; A[] holds ks 0..3 ----
  {
    f16x8 A2[4];
#pragma unroll
    for (int ct = 0; ct < 4; ++ct) A2[ct] = wfp[(4 + ct) * 64 + lane];
    f32x4 facc = {};
#pragma unroll
    for (int ks = 0; ks < 4; ++ks) {
      f16x8 b = *(const f16x8*)(hb + swz(wid * 16 + (lane & 15), ks * 64 + g * 16));
      facc = __builtin_amdgcn_mfma_f32_16x16x32_f16(A[ks], b, facc, 0, 0, 0);
    }
#pragma unroll
    for (int ks = 4; ks < 8; ++ks) {
      f16x8 b = *(const f16x8*)(hb + swz(wid * 16 + (lane & 15), ks * 64 + g * 16));
      facc = __builtin_amdgcn_mfma_f32_16x16x32_f16(A2[ks - 4], b, facc, 0, 0, 0);
    }
    if (g == 0) {
      size_t r = (size_t)tile * BT + wid * 16 + (lane & 15);
#pragma unroll
      for (int t = 0; t < 3; ++t)
        out[(r * MEXP + m) * ODIM + t] = facc[t] + bfin[m * ODIM + t];
    }
  }
}

extern "C" void kernel_launch(void* const* d_in, const int* in_sizes, int n_in,
                              void* d_out, int out_size, void* d_ws, size_t ws_size,
                              hipStream_t stream) {
  (void)in_sizes; (void)n_in; (void)out_size; (void)ws_size;
  const float* x  = (const float*)d_in[0];
  const float* w0 = (const float*)d_in[1];
  const float* b0 = (const float*)d_in[2];
  const float* w1 = (const float*)d_in[3];
  const float* b1 = (const float*)d_in[4];
  const float* w2 = (const float*)d_in[5];
  const float* b2 = (const float*)d_in[6];
  const float* w3 = (const float*)d_in[7];
  const float* b3 = (const float*)d_in[8];
  const float* wf = (const float*)d_in[9];
  const float* bf = (const float*)d_in[10];

  _Float16* wh  = (_Float16*)d_ws;                       // 3*64*65536 fp16 = 24 MB
  _Float16* wff = wh + (size_t)3 * MEXP * HDIM * HDIM;   // 64*4096 fp16 = 0.5 MB
  _Float16* w0f = wff + (size_t)MEXP * 16 * HDIM;        // 64*8192 fp16 = 1 MB

  prep_hidden<<<6144, 256, 0, stream>>>(w1, w2, w3, wh);
  prep_wf<<<128, 256, 0, stream>>>(wf, wff);
  prep_w0<<<256, 256, 0, stream>>>(w0, w0f);
  siren_fused<<<8192, 256, 0, stream>>>(x, b0, b1, b2, b3, bf, w0f, wh, wff,
                                        (float*)d_out);
}